// Round 12
// baseline (9185.481 us; speedup 1.0000x reference)
//
#include <hip/hip_runtime.h>
#include <math.h>
#include <stdint.h>

#define HIDDEN 2048
#define TSTEPS 1024
#define NWG 256
#define TPB 512
#define UPW 8           // hidden units per WG
#define CPT 16          // columns per thread

__device__ __forceinline__ float sigmoidf_(float x) { return 1.0f / (1.0f + __expf(-x)); }

// Exact per-byte nonzero indicator: LSB of each byte = (byte != 0).
// Masked folds -> no cross-byte contamination (no false pass/fail).
__device__ __forceinline__ uint64_t nzbytes(uint64_t x) {
    uint64_t t = (x | (x >> 4)) & 0x0F0F0F0F0F0F0F0FULL;
    t = (t | (t >> 2)) & 0x0303030303030303ULL;
    t = (t | (t >> 1)) & 0x0101010101010101ULL;
    return t;
}

// v12: direct consumer detect. Producers byte-store their step flag into a
// 256-byte array (2 cache lines). Every WG's wave 7 polls all 256 flags
// (32 lanes x 8B agent loads, wave-coalesced), validates bytes in {s, s+1}
// (global skew <= 1 by causality), LDS-broadcasts. No watcher, no go hop.
// Data path = v6-proven: fp32 hhist at per-step fresh addresses, agent qword
// stores + vmcnt(0) ack BEFORE the flag byte store; consumers read h with
// plain cached float4 loads (fresh lines miss -> fetch acked data from IF).
__global__ __launch_bounds__(TPB, 2)
void lstm_v12(const float* __restrict__ features,
              const float* __restrict__ pc,
              const float* __restrict__ W_ih,
              const float* __restrict__ W_hh,
              const float* __restrict__ b_ih,
              const float* __restrict__ b_hh,
              const float* __restrict__ W_fc,
              const float* __restrict__ b_fc,
              float* __restrict__ out,
              uint8_t* __restrict__ flags8,  // 256 bytes, memset 0 per launch
              float*   __restrict__ hhist)   // (TSTEPS+1)*HIDDEN floats, slot s = h_s
{
    const int b    = blockIdx.x;
    const int t    = threadIdx.x;
    const int lane = t & 63;
    const int wave = t >> 6;
    const int g    = t & 3;        // gate block 0..3 (i,f,g,o)
    const int cc   = t >> 2;       // column-chunk 0..127
    const int col0 = cc * CPT;

    // Invalidate caches across graph replays before any cached read of ws.
    __builtin_amdgcn_fence(__ATOMIC_ACQUIRE, "agent");

    __shared__ float pc_sh[2 * TSTEPS];
    __shared__ float red[8 * 32];
    __shared__ float outred[16];
    __shared__ int   ls_go;        // step gate broadcast (LDS)

    if (t == 0) ls_go = 0;

    {   // point cloud -> LDS
        const float4* p4 = reinterpret_cast<const float4*>(pc);
        reinterpret_cast<float4*>(pc_sh)[t] = p4[t];
    }

    // W_hh slice -> registers: w[ji][k] = W_hh[g*2048 + b*8 + ji][col0 + k]
    float w[UPW][CPT];
    {
        const int baserow = g * HIDDEN + b * UPW;
        #pragma unroll
        for (int ji = 0; ji < UPW; ++ji) {
            const float4* src = reinterpret_cast<const float4*>(
                W_hh + (size_t)(baserow + ji) * HIDDEN + col0);
            float4 a0 = src[0], a1 = src[1], a2 = src[2], a3 = src[3];
            w[ji][0]  = a0.x; w[ji][1]  = a0.y; w[ji][2]  = a0.z; w[ji][3]  = a0.w;
            w[ji][4]  = a1.x; w[ji][5]  = a1.y; w[ji][6]  = a1.z; w[ji][7]  = a1.w;
            w[ji][8]  = a2.x; w[ji][9]  = a2.y; w[ji][10] = a2.z; w[ji][11] = a2.w;
            w[ji][12] = a3.x; w[ji][13] = a3.y; w[ji][14] = a3.z; w[ji][15] = a3.w;
        }
    }

    // per-row constants + cell state for wave 0 (row id l = lane&31: gate = l>>3, unit = l&7)
    float bias_r = 0.0f, wi0_r = 0.0f, wi1_r = 0.0f, creg = 0.0f;
    if (wave == 0) {
        const int l   = lane & 31;
        const int row = (l >> 3) * HIDDEN + b * UPW + (l & 7);
        bias_r = b_ih[row] + b_hh[row];
        wi0_r  = W_ih[row * 2 + 0];
        wi1_r  = W_ih[row * 2 + 1];
    }
    __syncthreads();   // covers pc_sh + ls_go init

    const uint64_t* fq = reinterpret_cast<const uint64_t*>(flags8);
    const uint64_t  k1 = 0x0101010101010101ULL;

    // ---- recurrence: ONE __syncthreads per step ----
    for (int s = 0; s < TSTEPS; ++s) {
        const int rot = (s >= 1) && (b == ((s - 1) & 255));   // this WG emits out[s-1]

        // ---- gate: all 256 flags in {s, s+1} (mod 256) ----
        if (s >= 1) {
            if (wave == 7) {
                const uint64_t e0 = k1 * (uint64_t)(s & 255);
                const uint64_t e1 = k1 * (uint64_t)((s + 1) & 255);
                for (;;) {
                    uint64_t q = e0;
                    if (lane < 32) {
                        q = __hip_atomic_load(fq + lane, __ATOMIC_RELAXED,
                                              __HIP_MEMORY_SCOPE_AGENT);
                    }
                    const uint64_t bad = nzbytes(q ^ e0) & nzbytes(q ^ e1);
                    if (__all(bad == 0)) break;
                }
                if (lane == 0) {
                    __hip_atomic_store(&ls_go, s, __ATOMIC_RELAXED,
                                       __HIP_MEMORY_SCOPE_WORKGROUP);
                }
            } else {
                while (__hip_atomic_load(&ls_go, __ATOMIC_RELAXED,
                                         __HIP_MEMORY_SCOPE_WORKGROUP) < s) {}
            }
        }

        // ---- load h_s slice (plain cached; fresh address every step) ----
        float hr[CPT];
        {
            const float* hsrc = (s == 0) ? features : (hhist + (size_t)s * HIDDEN);
            #pragma unroll
            for (int k = 0; k < CPT; k += 4) {
                float4 hv = *reinterpret_cast<const float4*>(hsrc + col0 + k);
                hr[k] = hv.x; hr[k + 1] = hv.y; hr[k + 2] = hv.z; hr[k + 3] = hv.w;
            }
        }

        // ---- FMA phase ----
        float acc[UPW];
        #pragma unroll
        for (int ji = 0; ji < UPW; ++ji) acc[ji] = 0.0f;
        #pragma unroll
        for (int k = 0; k < CPT; ++k) {
            #pragma unroll
            for (int ji = 0; ji < UPW; ++ji) acc[ji] += w[ji][k] * hr[k];
        }
        #pragma unroll
        for (int m = 4; m < 64; m <<= 1) {
            #pragma unroll
            for (int ji = 0; ji < UPW; ++ji) acc[ji] += __shfl_xor(acc[ji], m);
        }
        if (lane < 4) {
            #pragma unroll
            for (int ji = 0; ji < UPW; ++ji) red[wave * 32 + lane * 8 + ji] = acc[ji];
        }

        // fc partials for out[s-1] (rotating WG; rides barrier (a))
        if (rot) {
            float po0 = 0.0f, po1 = 0.0f;
            #pragma unroll
            for (int k = 0; k < CPT; ++k) {
                po0 += hr[k] * W_fc[col0 + k];
                po1 += hr[k] * W_fc[HIDDEN + col0 + k];
            }
            #pragma unroll
            for (int m = 1; m < 64; m <<= 1) {
                po0 += __shfl_xor(po0, m);
                po1 += __shfl_xor(po1, m);
            }
            if (lane == 0) { outred[wave * 2 + 0] = po0; outred[wave * 2 + 1] = po1; }
        }
        __syncthreads();   // (a) red[] + outred[] ready

        if (wave == 0) {
            // final reduce + gates + publish
            const int l = lane & 31;
            float sum = 0.0f;
            #pragma unroll
            for (int ww = 0; ww < 8; ++ww) sum += red[ww * 32 + l];
            const float x0 = pc_sh[2 * s], x1 = pc_sh[2 * s + 1];
            const float gate = sum + bias_r + wi0_r * x0 + wi1_r * x1;
            const float iv = __shfl(gate, (lane & 7));
            const float fv = __shfl(gate, 8 + (lane & 7));
            const float gv = __shfl(gate, 16 + (lane & 7));
            const float ov = __shfl(gate, 24 + (lane & 7));
            const float cnew = sigmoidf_(fv) * creg + sigmoidf_(iv) * tanhf(gv);
            const float hnew = sigmoidf_(ov) * tanhf(cnew);
            creg = cnew;   // lane tracks unit lane&7
            const uint32_t hb = __float_as_uint(hnew);

            // publish 8 floats as 4 write-through qword stores
            const uint32_t lo = __shfl(hb, 2 * (lane & 3));
            const uint32_t hi = __shfl(hb, 2 * (lane & 3) + 1);
            if (lane < 4) {
                const uint64_t qv = (uint64_t)lo | ((uint64_t)hi << 32);
                uint64_t* dst = reinterpret_cast<uint64_t*>(
                    hhist + (size_t)(s + 1) * HIDDEN + b * UPW) + lane;
                __hip_atomic_store(dst, qv, __ATOMIC_RELAXED, __HIP_MEMORY_SCOPE_AGENT);
            }
            // data acked at the coherence point before the flag byte is visible
            asm volatile("s_waitcnt vmcnt(0)" ::: "memory");
            if (lane == 0) {
                __hip_atomic_store(flags8 + b, (uint8_t)((s + 1) & 255),
                                   __ATOMIC_RELAXED, __HIP_MEMORY_SCOPE_AGENT);
            }
        }

        // out[s-1] final sum (outred valid since (a))
        if (rot && t == 64) {
            float o0 = 0.0f, o1 = 0.0f;
            #pragma unroll
            for (int ww = 0; ww < 8; ++ww) { o0 += outred[ww * 2]; o1 += outred[ww * 2 + 1]; }
            out[(s - 1) * 2 + 0] = 0.25f * o0 + b_fc[0];
            out[(s - 1) * 2 + 1] = 0.25f * o1 + b_fc[1];
        }
        // no trailing barrier: the gate at the top of the next iteration orders
        // red[] reuse (gate s+1 requires this WG's flag s+1, which wave 0 stores
        // only after reading red[] at step s).
    }

    // ---- epilogue: out[T-1] = fc(h_T); (T-1)&255 = 255 -> WG 255 ----
    if (b == NWG - 1) {
        // gate TSTEPS: flags must all equal TSTEPS (mod 256). While waiting the
        // observable set is {TSTEPS-1, TSTEPS}; accept {TSTEPS, TSTEPS+1}.
        if (wave == 7) {
            const uint64_t e0 = k1 * (uint64_t)(TSTEPS & 255);
            const uint64_t e1 = k1 * (uint64_t)((TSTEPS + 1) & 255);
            for (;;) {
                uint64_t q = e0;
                if (lane < 32) {
                    q = __hip_atomic_load(fq + lane, __ATOMIC_RELAXED,
                                          __HIP_MEMORY_SCOPE_AGENT);
                }
                const uint64_t bad = nzbytes(q ^ e0) & nzbytes(q ^ e1);
                if (__all(bad == 0)) break;
            }
            if (lane == 0) {
                __hip_atomic_store(&ls_go, TSTEPS, __ATOMIC_RELAXED,
                                   __HIP_MEMORY_SCOPE_WORKGROUP);
            }
        } else {
            while (__hip_atomic_load(&ls_go, __ATOMIC_RELAXED,
                                     __HIP_MEMORY_SCOPE_WORKGROUP) < TSTEPS) {}
        }

        const float* hsrc = hhist + (size_t)TSTEPS * HIDDEN;
        float po0 = 0.0f, po1 = 0.0f;
        #pragma unroll
        for (int k = 0; k < CPT; ++k) {
            const float hv = hsrc[col0 + k];
            po0 += hv * W_fc[col0 + k];
            po1 += hv * W_fc[HIDDEN + col0 + k];
        }
        #pragma unroll
        for (int m = 1; m < 64; m <<= 1) {
            po0 += __shfl_xor(po0, m);
            po1 += __shfl_xor(po1, m);
        }
        if (lane == 0) { outred[wave * 2 + 0] = po0; outred[wave * 2 + 1] = po1; }
        __syncthreads();
        if (t == 0) {
            float o0 = 0.0f, o1 = 0.0f;
            #pragma unroll
            for (int ww = 0; ww < 8; ++ww) { o0 += outred[ww * 2]; o1 += outred[ww * 2 + 1]; }
            out[(TSTEPS - 1) * 2 + 0] = 0.25f * o0 + b_fc[0];
            out[(TSTEPS - 1) * 2 + 1] = 0.25f * o1 + b_fc[1];
        }
    }
}

extern "C" void kernel_launch(void* const* d_in, const int* in_sizes, int n_in,
                              void* d_out, int out_size, void* d_ws, size_t ws_size,
                              hipStream_t stream) {
    const float* features = (const float*)d_in[0];
    const float* pc       = (const float*)d_in[1];
    const float* W_ih     = (const float*)d_in[2];
    const float* W_hh     = (const float*)d_in[3];
    const float* b_ih     = (const float*)d_in[4];
    const float* b_hh     = (const float*)d_in[5];
    const float* W_fc     = (const float*)d_in[6];
    const float* b_fc     = (const float*)d_in[7];
    float* out = (float*)d_out;

    uint8_t* flags8 = (uint8_t*)d_ws;                    // 256 B (2 lines)
    float*   hhist  = (float*)((char*)d_ws + 4096);      // 8.4 MB, page-aligned

    // flags must start at 0 every call (graph replays don't re-poison ws)
    hipMemsetAsync(d_ws, 0, 4096, stream);

    hipLaunchKernelGGL(lstm_v12, dim3(NWG), dim3(TPB), 0, stream,
                       features, pc, W_ih, W_hh, b_ih, b_hh, W_fc, b_fc,
                       out, flags8, hhist);
}

// Round 13
// 3599.844 us; speedup vs baseline: 2.5516x; 2.5516x over previous
//
#include <hip/hip_runtime.h>
#include <math.h>
#include <stdint.h>

#define HIDDEN 2048
#define TSTEPS 1024
#define NWG 256
#define TPB 512
#define UPW 8           // hidden units per WG
#define CPT 16          // columns per thread
#define FLAG_STRIDE 32  // ints per flag/go line (128 B)
#define GO_STRIDE 32

__device__ __forceinline__ float sigmoidf_(float x) { return 1.0f / (1.0f + __expf(-x)); }

// v13 = v10 (one barrier/step, WG255-wave7 watcher, agent-scope tree) with:
//  - go poll by wave 7 only (4 waves/go-line fan-in), LDS ls_go relay to waves 0-6
//  - rot WG's wave 0 publishes BEFORE doing its fc partial (straggler shave)
__global__ __launch_bounds__(TPB, 2)
void lstm_v13(const float* __restrict__ features,
              const float* __restrict__ pc,
              const float* __restrict__ W_ih,
              const float* __restrict__ W_hh,
              const float* __restrict__ b_ih,
              const float* __restrict__ b_hh,
              const float* __restrict__ W_fc,
              const float* __restrict__ b_fc,
              float* __restrict__ out,
              int*   __restrict__ flags,   // NWG lines x FLAG_STRIDE ints, memset 0
              int*   __restrict__ go,      // 64 lines x GO_STRIDE ints, memset 0
              float* __restrict__ hhist)   // (TSTEPS+1)*HIDDEN floats, slot s = h_s
{
    const int b    = blockIdx.x;
    const int t    = threadIdx.x;
    const int lane = t & 63;
    const int wave = t >> 6;
    const int g    = t & 3;        // gate block 0..3 (i,f,g,o)
    const int cc   = t >> 2;       // column-chunk 0..127
    const int col0 = cc * CPT;
    const bool isw255 = (b == NWG - 1);

    // Invalidate caches across graph replays before any cached read of ws.
    __builtin_amdgcn_fence(__ATOMIC_ACQUIRE, "agent");

    __shared__ float pc_sh[2 * TSTEPS];
    __shared__ float red[8 * 32];
    __shared__ float outred[16];
    __shared__ int   ls_go;        // per-WG step gate (LDS relay)

    if (t == 0) ls_go = 0;

    {   // point cloud -> LDS
        const float4* p4 = reinterpret_cast<const float4*>(pc);
        reinterpret_cast<float4*>(pc_sh)[t] = p4[t];
    }

    // W_hh slice -> registers: w[ji][k] = W_hh[g*2048 + b*8 + ji][col0 + k]
    float w[UPW][CPT];
    {
        const int baserow = g * HIDDEN + b * UPW;
        #pragma unroll
        for (int ji = 0; ji < UPW; ++ji) {
            const float4* src = reinterpret_cast<const float4*>(
                W_hh + (size_t)(baserow + ji) * HIDDEN + col0);
            float4 a0 = src[0], a1 = src[1], a2 = src[2], a3 = src[3];
            w[ji][0]  = a0.x; w[ji][1]  = a0.y; w[ji][2]  = a0.z; w[ji][3]  = a0.w;
            w[ji][4]  = a1.x; w[ji][5]  = a1.y; w[ji][6]  = a1.z; w[ji][7]  = a1.w;
            w[ji][8]  = a2.x; w[ji][9]  = a2.y; w[ji][10] = a2.z; w[ji][11] = a2.w;
            w[ji][12] = a3.x; w[ji][13] = a3.y; w[ji][14] = a3.z; w[ji][15] = a3.w;
        }
    }

    // per-row constants + cell state for wave 0 (row id l = lane&31: gate = l>>3, unit = l&7)
    float bias_r = 0.0f, wi0_r = 0.0f, wi1_r = 0.0f, creg = 0.0f;
    if (wave == 0) {
        const int l   = lane & 31;
        const int row = (l >> 3) * HIDDEN + b * UPW + (l & 7);
        bias_r = b_ih[row] + b_hh[row];
        wi0_r  = W_ih[row * 2 + 0];
        wi1_r  = W_ih[row * 2 + 1];
    }
    __syncthreads();   // covers pc_sh + ls_go init

    const int* gop = go + (size_t)(b >> 2) * GO_STRIDE;

    // ---- recurrence: ONE __syncthreads per step ----
    for (int s = 0; s < TSTEPS; ++s) {
        const int rot = (s >= 1) && (b == ((s - 1) & 255));   // this WG emits out[s-1]

        // ---- step gate ----
        if (s >= 1) {
            if (isw255) {
                // ls_go was set by this WG's own wave 7 (watcher) last step
                while (__hip_atomic_load(&ls_go, __ATOMIC_RELAXED,
                                         __HIP_MEMORY_SCOPE_WORKGROUP) < s) {}
            } else if (wave == 7) {
                // only wave 7 touches the fabric: 4 waves per go line
                while (__hip_atomic_load(gop, __ATOMIC_RELAXED,
                                         __HIP_MEMORY_SCOPE_AGENT) < s) {}
                if (lane == 0) {
                    __hip_atomic_store(&ls_go, s, __ATOMIC_RELAXED,
                                       __HIP_MEMORY_SCOPE_WORKGROUP);
                }
            } else {
                while (__hip_atomic_load(&ls_go, __ATOMIC_RELAXED,
                                         __HIP_MEMORY_SCOPE_WORKGROUP) < s) {}
            }
        }

        // ---- load h_s slice (plain cached; fresh address every step) ----
        float hr[CPT];
        {
            const float* hsrc = (s == 0) ? features : (hhist + (size_t)s * HIDDEN);
            #pragma unroll
            for (int k = 0; k < CPT; k += 4) {
                float4 hv = *reinterpret_cast<const float4*>(hsrc + col0 + k);
                hr[k] = hv.x; hr[k + 1] = hv.y; hr[k + 2] = hv.z; hr[k + 3] = hv.w;
            }
        }

        // ---- FMA phase ----
        float acc[UPW];
        #pragma unroll
        for (int ji = 0; ji < UPW; ++ji) acc[ji] = 0.0f;
        #pragma unroll
        for (int k = 0; k < CPT; ++k) {
            #pragma unroll
            for (int ji = 0; ji < UPW; ++ji) acc[ji] += w[ji][k] * hr[k];
        }
        #pragma unroll
        for (int m = 4; m < 64; m <<= 1) {
            #pragma unroll
            for (int ji = 0; ji < UPW; ++ji) acc[ji] += __shfl_xor(acc[ji], m);
        }
        if (lane < 4) {
            #pragma unroll
            for (int ji = 0; ji < UPW; ++ji) red[wave * 32 + lane * 8 + ji] = acc[ji];
        }

        // fc partials for out[s-1]: waves 1-7 only (wave 0 defers until after publish)
        if (rot && wave != 0) {
            float po0 = 0.0f, po1 = 0.0f;
            #pragma unroll
            for (int k = 0; k < CPT; ++k) {
                po0 += hr[k] * W_fc[col0 + k];
                po1 += hr[k] * W_fc[HIDDEN + col0 + k];
            }
            #pragma unroll
            for (int m = 1; m < 64; m <<= 1) {
                po0 += __shfl_xor(po0, m);
                po1 += __shfl_xor(po1, m);
            }
            if (lane == 0) { outred[wave * 2 + 0] = po0; outred[wave * 2 + 1] = po1; }
        }
        __syncthreads();   // (a) red[] + outred[1..7] ready

        if (wave == 0) {
            // final reduce + gates + publish FIRST (critical path)
            const int l = lane & 31;
            float sum = 0.0f;
            #pragma unroll
            for (int ww = 0; ww < 8; ++ww) sum += red[ww * 32 + l];
            const float x0 = pc_sh[2 * s], x1 = pc_sh[2 * s + 1];
            const float gate = sum + bias_r + wi0_r * x0 + wi1_r * x1;
            const float iv = __shfl(gate, (lane & 7));
            const float fv = __shfl(gate, 8 + (lane & 7));
            const float gv = __shfl(gate, 16 + (lane & 7));
            const float ov = __shfl(gate, 24 + (lane & 7));
            const float cnew = sigmoidf_(fv) * creg + sigmoidf_(iv) * tanhf(gv);
            const float hnew = sigmoidf_(ov) * tanhf(cnew);
            creg = cnew;   // lane tracks unit lane&7
            const uint32_t hb = __float_as_uint(hnew);

            // publish 8 floats as 4 write-through qword stores
            const uint32_t lo = __shfl(hb, 2 * (lane & 3));
            const uint32_t hi = __shfl(hb, 2 * (lane & 3) + 1);
            if (lane < 4) {
                const uint64_t qv = (uint64_t)lo | ((uint64_t)hi << 32);
                uint64_t* dst = reinterpret_cast<uint64_t*>(
                    hhist + (size_t)(s + 1) * HIDDEN + b * UPW) + lane;
                __hip_atomic_store(dst, qv, __ATOMIC_RELAXED, __HIP_MEMORY_SCOPE_AGENT);
            }
            // data acked at the coherence point before the flag becomes visible
            asm volatile("s_waitcnt vmcnt(0)" ::: "memory");
            if (lane == 0) {
                __hip_atomic_store(flags + (size_t)b * FLAG_STRIDE, s + 1,
                                   __ATOMIC_RELAXED, __HIP_MEMORY_SCOPE_AGENT);
            }

            // deferred fc work for the rotating WG (off the global critical path)
            if (rot) {
                float po0 = 0.0f, po1 = 0.0f;
                #pragma unroll
                for (int k = 0; k < CPT; ++k) {
                    po0 += hr[k] * W_fc[col0 + k];
                    po1 += hr[k] * W_fc[HIDDEN + col0 + k];
                }
                #pragma unroll
                for (int m = 1; m < 64; m <<= 1) {
                    po0 += __shfl_xor(po0, m);
                    po1 += __shfl_xor(po1, m);
                }
                if (lane == 0) {
                    outred[0] = po0; outred[1] = po1;
                    float o0 = 0.0f, o1 = 0.0f;
                    #pragma unroll
                    for (int ww = 0; ww < 8; ++ww) { o0 += outred[ww * 2]; o1 += outred[ww * 2 + 1]; }
                    out[(s - 1) * 2 + 0] = 0.25f * o0 + b_fc[0];
                    out[(s - 1) * 2 + 1] = 0.25f * o1 + b_fc[1];
                }
            }
        }

        // watcher: WG 255 wave 7 — starts at (a), overlaps all gate compute
        if (isw255 && wave == 7) {
            const int l4 = lane * 4;
            const int* f0p = flags + (size_t)(l4 + 0) * FLAG_STRIDE;
            const int* f1p = flags + (size_t)(l4 + 1) * FLAG_STRIDE;
            const int* f2p = flags + (size_t)(l4 + 2) * FLAG_STRIDE;
            const int* f3p = flags + (size_t)(l4 + 3) * FLAG_STRIDE;
            for (;;) {
                const int f0 = __hip_atomic_load(f0p, __ATOMIC_RELAXED, __HIP_MEMORY_SCOPE_AGENT);
                const int f1 = __hip_atomic_load(f1p, __ATOMIC_RELAXED, __HIP_MEMORY_SCOPE_AGENT);
                const int f2 = __hip_atomic_load(f2p, __ATOMIC_RELAXED, __HIP_MEMORY_SCOPE_AGENT);
                const int f3 = __hip_atomic_load(f3p, __ATOMIC_RELAXED, __HIP_MEMORY_SCOPE_AGENT);
                const bool ok = (f0 >= s + 1) & (f1 >= s + 1) & (f2 >= s + 1) & (f3 >= s + 1);
                if (__all(ok)) break;
            }
            // fan-out: 64 agent go lines + LDS self-gate
            __hip_atomic_store(go + (size_t)lane * GO_STRIDE, s + 1,
                               __ATOMIC_RELAXED, __HIP_MEMORY_SCOPE_AGENT);
            if (lane == 0) {
                __hip_atomic_store(&ls_go, s + 1, __ATOMIC_RELAXED,
                                   __HIP_MEMORY_SCOPE_WORKGROUP);
            }
        }
        // no trailing barrier: the gate at the top of the next iteration orders
        // red[] reuse (gate s+1 requires this WG's flag s+1, which wave 0 stores
        // only after reading red[] at step s).
    }

    // ---- epilogue: out[T-1] = fc(h_T); (T-1)&255 = 255 -> WG 255 ----
    if (isw255) {
        while (__hip_atomic_load(&ls_go, __ATOMIC_RELAXED,
                                 __HIP_MEMORY_SCOPE_WORKGROUP) < TSTEPS) {}
        const float* hsrc = hhist + (size_t)TSTEPS * HIDDEN;
        float po0 = 0.0f, po1 = 0.0f;
        #pragma unroll
        for (int k = 0; k < CPT; ++k) {
            const float hv = hsrc[col0 + k];
            po0 += hv * W_fc[col0 + k];
            po1 += hv * W_fc[HIDDEN + col0 + k];
        }
        #pragma unroll
        for (int m = 1; m < 64; m <<= 1) {
            po0 += __shfl_xor(po0, m);
            po1 += __shfl_xor(po1, m);
        }
        if (lane == 0) { outred[wave * 2 + 0] = po0; outred[wave * 2 + 1] = po1; }
        __syncthreads();
        if (t == 0) {
            float o0 = 0.0f, o1 = 0.0f;
            #pragma unroll
            for (int ww = 0; ww < 8; ++ww) { o0 += outred[ww * 2]; o1 += outred[ww * 2 + 1]; }
            out[(TSTEPS - 1) * 2 + 0] = 0.25f * o0 + b_fc[0];
            out[(TSTEPS - 1) * 2 + 1] = 0.25f * o1 + b_fc[1];
        }
    }
}

extern "C" void kernel_launch(void* const* d_in, const int* in_sizes, int n_in,
                              void* d_out, int out_size, void* d_ws, size_t ws_size,
                              hipStream_t stream) {
    const float* features = (const float*)d_in[0];
    const float* pc       = (const float*)d_in[1];
    const float* W_ih     = (const float*)d_in[2];
    const float* W_hh     = (const float*)d_in[3];
    const float* b_ih     = (const float*)d_in[4];
    const float* b_hh     = (const float*)d_in[5];
    const float* W_fc     = (const float*)d_in[6];
    const float* b_fc     = (const float*)d_in[7];
    float* out = (float*)d_out;

    const size_t flags_bytes = (size_t)NWG * FLAG_STRIDE * sizeof(int);  // 32 KB
    const size_t go_bytes    = (size_t)64 * GO_STRIDE * sizeof(int);     //  8 KB
    const size_t hh_off      = flags_bytes + go_bytes;                   // 40 KB

    int*   flags = (int*)d_ws;
    int*   go    = (int*)((char*)d_ws + flags_bytes);
    float* hhist = (float*)((char*)d_ws + hh_off);

    // flags/go must start at 0 every call (graph replays don't re-poison ws)
    hipMemsetAsync(d_ws, 0, hh_off, stream);

    hipLaunchKernelGGL(lstm_v13, dim3(NWG), dim3(TPB), 0, stream,
                       features, pc, W_ih, W_hh, b_ih, b_hh, W_fc, b_fc,
                       out, flags, go, hhist);
}